// Round 1
// baseline (1791.685 us; speedup 1.0000x reference)
//
#include <hip/hip_runtime.h>

namespace {

constexpr int QN = 4;
constexpr int MR = 8192;   // B*S
constexpr int DD = 768;
constexpr int HH = 512;
constexpr int NN = 1024;

// ---------------- fused GEMM + BatchNorm(eval) + ReLU ----------------
// C[M,N] = relu(bn(A[M,K] @ W[K,N] + bias))
// Tile: BM = 64*ROWG, BN = 128, BK = 16; 256 threads, (4*ROWG)x8 per thread.
template<int ROWG>
__global__ __launch_bounds__(256)
void gemm_bn_relu(const float* __restrict__ A, const float* __restrict__ W,
                  const float* __restrict__ bias, const float* __restrict__ gam,
                  const float* __restrict__ beta, const float* __restrict__ mean,
                  const float* __restrict__ var, float* __restrict__ C,
                  int N_, int K_)
{
    constexpr int BM = 64 * ROWG;
    constexpr int BN = 128;
    constexpr int BK = 16;
    __shared__ float As[BK][BM + 4];   // transposed A tile
    __shared__ float Bs[BK][BN + 4];
    const int t   = threadIdx.x;
    const int bn0 = blockIdx.x * BN;
    const int bm0 = blockIdx.y * BM;
    const int tx  = t & 15;
    const int ty  = t >> 4;

    float acc[4 * ROWG][8];
    #pragma unroll
    for (int i = 0; i < 4 * ROWG; ++i)
        #pragma unroll
        for (int j = 0; j < 8; ++j) acc[i][j] = 0.f;

    for (int k0 = 0; k0 < K_; k0 += BK) {
        // A tile: BM x 16, store transposed As[k][m]
        #pragma unroll
        for (int p = 0; p < ROWG; ++p) {
            int fid = p * 256 + t;
            int row = fid >> 2;
            int c4  = (fid & 3) << 2;
            float4 v = *(const float4*)(A + (size_t)(bm0 + row) * K_ + k0 + c4);
            As[c4 + 0][row] = v.x; As[c4 + 1][row] = v.y;
            As[c4 + 2][row] = v.z; As[c4 + 3][row] = v.w;
        }
        // B tile: 16 x 128, natural layout
        #pragma unroll
        for (int p = 0; p < 2; ++p) {
            int fid = p * 256 + t;
            int kk  = fid >> 5;
            int c4  = (fid & 31) << 2;
            float4 v = *(const float4*)(W + (size_t)(k0 + kk) * N_ + bn0 + c4);
            *(float4*)&Bs[kk][c4] = v;
        }
        __syncthreads();
        #pragma unroll
        for (int k = 0; k < BK; ++k) {
            float a[4 * ROWG], b[8];
            #pragma unroll
            for (int g = 0; g < ROWG; ++g) {
                float4 ta = *(const float4*)&As[k][g * 64 + ty * 4];
                a[4 * g + 0] = ta.x; a[4 * g + 1] = ta.y;
                a[4 * g + 2] = ta.z; a[4 * g + 3] = ta.w;
            }
            {
                float4 tb0 = *(const float4*)&Bs[k][tx * 4];
                float4 tb1 = *(const float4*)&Bs[k][64 + tx * 4];
                b[0] = tb0.x; b[1] = tb0.y; b[2] = tb0.z; b[3] = tb0.w;
                b[4] = tb1.x; b[5] = tb1.y; b[6] = tb1.z; b[7] = tb1.w;
            }
            #pragma unroll
            for (int i = 0; i < 4 * ROWG; ++i)
                #pragma unroll
                for (int j = 0; j < 8; ++j)
                    acc[i][j] = fmaf(a[i], b[j], acc[i][j]);
        }
        __syncthreads();
    }

    // epilogue: bn + relu.  out = acc*scale + shift
    float scale[8], shift[8];
    #pragma unroll
    for (int j = 0; j < 8; ++j) {
        int c = bn0 + ((j < 4) ? (tx * 4 + j) : (64 + tx * 4 + (j - 4)));
        float sc = gam[c] * rsqrtf(var[c] + 1e-5f);
        scale[j] = sc;
        shift[j] = (bias[c] - mean[c]) * sc + beta[c];
    }
    #pragma unroll
    for (int i = 0; i < 4 * ROWG; ++i) {
        int r = bm0 + (i >> 2) * 64 + ty * 4 + (i & 3);
        float4 o0, o1;
        o0.x = fmaxf(0.f, fmaf(acc[i][0], scale[0], shift[0]));
        o0.y = fmaxf(0.f, fmaf(acc[i][1], scale[1], shift[1]));
        o0.z = fmaxf(0.f, fmaf(acc[i][2], scale[2], shift[2]));
        o0.w = fmaxf(0.f, fmaf(acc[i][3], scale[3], shift[3]));
        o1.x = fmaxf(0.f, fmaf(acc[i][4], scale[4], shift[4]));
        o1.y = fmaxf(0.f, fmaf(acc[i][5], scale[5], shift[5]));
        o1.z = fmaxf(0.f, fmaf(acc[i][6], scale[6], shift[6]));
        o1.w = fmaxf(0.f, fmaf(acc[i][7], scale[7], shift[7]));
        *(float4*)(C + (size_t)r * N_ + bn0 + tx * 4)      = o0;
        *(float4*)(C + (size_t)r * N_ + bn0 + 64 + tx * 4) = o1;
    }
}

// ---------------- fused per-row: softmax stats + entropy + latent +
//                  gumbel argmax + codebook gather + residual/qout update ----
__global__ __launch_bounds__(256)
void row_fuse(const float* __restrict__ z, const float* __restrict__ gum,
              const float* __restrict__ cb, const float* __restrict__ x,
              float* __restrict__ res, float* __restrict__ qout,
              float* __restrict__ ent, float* __restrict__ lat,
              float* __restrict__ idxf, int first)
{
    __shared__ float sm[8];
    __shared__ int   smi[4];
    __shared__ int   sidx;
    const int r   = blockIdx.x;
    const int t   = threadIdx.x;
    const int wid = t >> 6;
    const bool l0 = (t & 63) == 0;

    const float4 z4 = ((const float4*)(z   + (size_t)r * NN))[t];
    const float4 g4 = ((const float4*)(gum + (size_t)r * NN))[t];

    // 1) row max
    float mx = fmaxf(fmaxf(z4.x, z4.y), fmaxf(z4.z, z4.w));
    #pragma unroll
    for (int o = 1; o < 64; o <<= 1) mx = fmaxf(mx, __shfl_xor(mx, o, 64));
    if (l0) sm[wid] = mx;
    __syncthreads();
    mx = fmaxf(fmaxf(sm[0], sm[1]), fmaxf(sm[2], sm[3]));

    // 2) exp + sum
    float e0 = __expf(z4.x - mx), e1 = __expf(z4.y - mx);
    float e2 = __expf(z4.z - mx), e3 = __expf(z4.w - mx);
    float s = (e0 + e1) + (e2 + e3);
    #pragma unroll
    for (int o = 1; o < 64; o <<= 1) s += __shfl_xor(s, o, 64);
    if (l0) sm[4 + wid] = s;
    __syncthreads();
    s = (sm[4] + sm[5]) + (sm[6] + sm[7]);

    float inv = 1.0f / s;
    float q0 = e0 * inv, q1 = e1 * inv, q2 = e2 * inv, q3 = e3 * inv;

    // 3) entropy partial
    float ep = q0 * __logf(q0 + 1e-10f) + q1 * __logf(q1 + 1e-10f)
             + q2 * __logf(q2 + 1e-10f) + q3 * __logf(q3 + 1e-10f);
    #pragma unroll
    for (int o = 1; o < 64; o <<= 1) ep += __shfl_xor(ep, o, 64);

    // 4) latent loss
    float4 l4;
    l4.x = q0 * __logf(q0 * 1024.f + 1e-10f);
    l4.y = q1 * __logf(q1 * 1024.f + 1e-10f);
    l4.z = q2 * __logf(q2 * 1024.f + 1e-10f);
    l4.w = q3 * __logf(q3 * 1024.f + 1e-10f);
    ((float4*)(lat + (size_t)r * NN))[t] = l4;

    // 5) argmax(z + gumbel) with first-index tie-break (matches jnp.argmax)
    float bv = z4.x + g4.x; int bi = t * 4;
    { float v = z4.y + g4.y; if (v > bv) { bv = v; bi = t * 4 + 1; } }
    { float v = z4.z + g4.z; if (v > bv) { bv = v; bi = t * 4 + 2; } }
    { float v = z4.w + g4.w; if (v > bv) { bv = v; bi = t * 4 + 3; } }
    #pragma unroll
    for (int o = 1; o < 64; o <<= 1) {
        float ov = __shfl_xor(bv, o, 64);
        int   oi = __shfl_xor(bi, o, 64);
        if (ov > bv || (ov == bv && oi < bi)) { bv = ov; bi = oi; }
    }
    __syncthreads();                       // protect sm[4..7]/sm[0..3] reuse
    if (l0) { sm[wid] = ep; sm[4 + wid] = bv; smi[wid] = bi; }
    __syncthreads();
    if (t == 0) {
        ent[r] = -((sm[0] + sm[1]) + (sm[2] + sm[3]));
        float bbv = sm[4]; int bbi = smi[0];
        #pragma unroll
        for (int w = 1; w < 4; ++w) {
            if (sm[4 + w] > bbv || (sm[4 + w] == bbv && smi[w] < bbi)) {
                bbv = sm[4 + w]; bbi = smi[w];
            }
        }
        idxf[r] = (float)bbi;
        sidx = bbi;
    }
    __syncthreads();
    const int ci = sidx;

    // 6) z_q = codebook row; residual -= z_q; qout += z_q (init on first)
    if (t < DD / 4) {
        float4 c4 = ((const float4*)(cb + (size_t)ci * DD))[t];
        float4 rv, qv;
        if (first) {
            float4 xv = ((const float4*)(x + (size_t)r * DD))[t];
            rv.x = xv.x - c4.x; rv.y = xv.y - c4.y;
            rv.z = xv.z - c4.z; rv.w = xv.w - c4.w;
            qv = c4;
        } else {
            rv = ((const float4*)(res  + (size_t)r * DD))[t];
            qv = ((const float4*)(qout + (size_t)r * DD))[t];
            rv.x -= c4.x; rv.y -= c4.y; rv.z -= c4.z; rv.w -= c4.w;
            qv.x += c4.x; qv.y += c4.y; qv.z += c4.z; qv.w += c4.w;
        }
        ((float4*)(res  + (size_t)r * DD))[t] = rv;
        ((float4*)(qout + (size_t)r * DD))[t] = qv;
    }
}

} // namespace

extern "C" void kernel_launch(void* const* d_in, const int* in_sizes, int n_in,
                              void* d_out, int out_size, void* d_ws, size_t ws_size,
                              hipStream_t stream)
{
    const float* x    = (const float*)d_in[0];
    const float* cb   = (const float*)d_in[1];
    const float* pW1  = (const float*)d_in[2];
    const float* pb1  = (const float*)d_in[3];
    const float* pg1  = (const float*)d_in[4];
    const float* pbe1 = (const float*)d_in[5];
    const float* pm1  = (const float*)d_in[6];
    const float* pv1  = (const float*)d_in[7];
    const float* pW2  = (const float*)d_in[8];
    const float* pb2  = (const float*)d_in[9];
    const float* pg2  = (const float*)d_in[10];
    const float* pbe2 = (const float*)d_in[11];
    const float* pm2  = (const float*)d_in[12];
    const float* pv2  = (const float*)d_in[13];
    const float* dW1  = (const float*)d_in[14];
    const float* db1  = (const float*)d_in[15];
    const float* dg1  = (const float*)d_in[16];
    const float* dbe1 = (const float*)d_in[17];
    const float* dm1  = (const float*)d_in[18];
    const float* dv1  = (const float*)d_in[19];
    const float* dW2  = (const float*)d_in[20];
    const float* db2  = (const float*)d_in[21];
    const float* dg2  = (const float*)d_in[22];
    const float* dbe2 = (const float*)d_in[23];
    const float* dm2  = (const float*)d_in[24];
    const float* dv2  = (const float*)d_in[25];
    const float* gum  = (const float*)d_in[26];

    // output layout (floats): xhat | entropies | latent | indices | zs
    float* out  = (float*)d_out;
    float* xhat = out;
    float* ent  = xhat + (size_t)MR * DD;        // 6291456
    float* lat  = ent  + (size_t)QN * MR;        // +32768
    float* idxf = lat  + (size_t)QN * MR * NN;   // +33554432
    float* zs   = idxf + (size_t)QN * MR;        // +32768

    // workspace: residual | quantized_out | h / h_dec  (100.7 MB total)
    float* res  = (float*)d_ws;
    float* qo   = res + (size_t)MR * DD;
    float* hbuf = qo  + (size_t)MR * DD;         // holds [8192,512] or [8192,1536]

    dim3 blk(256);
    for (int i = 0; i < QN; ++i) {
        const float* Ain = (i == 0) ? x : res;
        hipLaunchKernelGGL((gemm_bn_relu<1>), dim3(HH / 128, MR / 64), blk, 0, stream,
            Ain, pW1 + (size_t)i * DD * HH, pb1 + i * HH, pg1 + i * HH, pbe1 + i * HH,
            pm1 + i * HH, pv1 + i * HH, hbuf, HH, DD);
        float* z_i = zs + (size_t)i * MR * NN;
        hipLaunchKernelGGL((gemm_bn_relu<2>), dim3(NN / 128, MR / 128), blk, 0, stream,
            hbuf, pW2 + (size_t)i * HH * NN, pb2 + i * NN, pg2 + i * NN, pbe2 + i * NN,
            pm2 + i * NN, pv2 + i * NN, z_i, NN, HH);
        hipLaunchKernelGGL(row_fuse, dim3(MR), blk, 0, stream,
            z_i, gum + (size_t)i * MR * NN, cb + (size_t)i * NN * DD, x, res, qo,
            ent + (size_t)i * MR, lat + (size_t)i * MR * NN, idxf + (size_t)i * MR,
            (int)(i == 0));
    }
    hipLaunchKernelGGL((gemm_bn_relu<2>), dim3(2 * DD / 128, MR / 128), blk, 0, stream,
        qo, dW1, db1, dg1, dbe1, dm1, dv1, hbuf, 2 * DD, DD);
    hipLaunchKernelGGL((gemm_bn_relu<2>), dim3(DD / 128, MR / 128), blk, 0, stream,
        hbuf, dW2, db2, dg2, dbe2, dm2, dv2, xhat, DD, 2 * DD);
}